// Round 1
// baseline (3919.378 us; speedup 1.0000x reference)
//
#include <hip/hip_runtime.h>
#include <cstdint>

// Problem constants: B=8, Cin=Cout=128, x is 128x128, out is 256x256.
#define SCALE_MAIN 0.029462782549439483f   // 1/sqrt(128*9)
#define LSCALE     0.044194173824159223f   // 1/sqrt(512)
#define CSCALE     0.029462782549439483f   // 1/sqrt(128*9)

static __device__ __forceinline__ float lrelu_s2(float v) {
  return (v > 0.f ? v : 0.2f * v) * 1.4142135623730951f;
}

// K0: fused effective kernel Keff[co][ci][parity(2x2)][tap(3x3)]
// Keff[ph][pw][a][b] = C2D[t_h(ph,a), t_w(pw,b)],
// C2D[th,tw] = sum_{u,v in [0,4)} bk[3-u][3-v] * w_scaled[th-1+u, tw-1+v]
// t(ph=0, a) = 2-2a ; t(ph=1, a) = 3-2a. bk[i][j] = k[i]k[j]/16, k={1,3,3,1}.
__global__ __launch_bounds__(256) void keff_kernel(const float* __restrict__ weight,
                                                   float* __restrict__ keff) {
  int idx = blockIdx.x * 256 + threadIdx.x;
  if (idx >= 128 * 128 * 36) return;
  int tap = idx % 9;
  int tmp = idx / 9;
  int par = tmp & 3;
  int cc  = tmp >> 2;            // co*128 + ci
  int ph = par >> 1, pw = par & 1;
  int a = tap / 3, b = tap % 3;
  int th = ph ? 3 - 2 * a : 2 - 2 * a;
  int tw = pw ? 3 - 2 * b : 2 - 2 * b;
  const float k4[4] = {1.f, 3.f, 3.f, 1.f};
  const float* wp = weight + cc * 9;
  float acc = 0.f;
  #pragma unroll
  for (int u = 0; u < 4; ++u) {
    int m = th - 1 + u;
    if (m < 0 || m > 2) continue;
    #pragma unroll
    for (int v = 0; v < 4; ++v) {
      int n = tw - 1 + v;
      if (n < 0 || n > 2) continue;
      acc += (k4[3 - u] * k4[3 - v] * (1.f / 16.f)) * wp[m * 3 + n];
    }
  }
  keff[idx] = acc * SCALE_MAIN;
}

// K1: s = lrelu(style @ (lin_w*lscale)^T + lin_b)*sqrt(2) -> smap[b][32768]
// One wave per 16 rows; style held in registers (8 batches x 8 k-vals per lane).
__global__ __launch_bounds__(256) void style_kernel(const float* __restrict__ style,
                                                    const float* __restrict__ lin_w,
                                                    const float* __restrict__ lin_b,
                                                    float* __restrict__ smap) {
  int wid = threadIdx.x >> 6, lane = threadIdx.x & 63;
  int gw = blockIdx.x * 4 + wid;          // 2048 waves, 16 rows each
  const float4* st4 = (const float4*)style;
  float s[8][8];
  #pragma unroll
  for (int b = 0; b < 8; ++b) {
    float4 a0 = st4[b * 128 + lane * 2];
    float4 a1 = st4[b * 128 + lane * 2 + 1];
    s[b][0] = a0.x; s[b][1] = a0.y; s[b][2] = a0.z; s[b][3] = a0.w;
    s[b][4] = a1.x; s[b][5] = a1.y; s[b][6] = a1.z; s[b][7] = a1.w;
  }
  for (int rr = 0; rr < 16; ++rr) {
    int j = gw * 16 + rr;
    const float4* wp = (const float4*)(lin_w + (size_t)j * 512);
    float4 w0 = wp[lane * 2], w1 = wp[lane * 2 + 1];
    float acc[8];
    #pragma unroll
    for (int b = 0; b < 8; ++b) {
      acc[b] = w0.x * s[b][0] + w0.y * s[b][1] + w0.z * s[b][2] + w0.w * s[b][3]
             + w1.x * s[b][4] + w1.y * s[b][5] + w1.z * s[b][6] + w1.w * s[b][7];
    }
    #pragma unroll
    for (int m = 32; m; m >>= 1) {
      #pragma unroll
      for (int b = 0; b < 8; ++b) acc[b] += __shfl_xor(acc[b], m, 64);
    }
    if (lane == 0) {
      float bias = lin_b[j];
      #pragma unroll
      for (int b = 0; b < 8; ++b)
        smap[(size_t)b * 32768 + j] = lrelu_s2(acc[b] * LSCALE + bias);
    }
  }
}

// K2: sw/sb = EqualConv3x3(upsample2(smap)) + bias, both convs share input reads.
__global__ __launch_bounds__(256) void modconv_kernel(const float* __restrict__ smap,
    const float* __restrict__ cw_w, const float* __restrict__ cw_b,
    const float* __restrict__ cb_w, const float* __restrict__ cb_b,
    float* __restrict__ sw, float* __restrict__ sb) {
  int co = blockIdx.x, b = blockIdx.y;
  int t = threadIdx.x;
  __shared__ float sm[256];
  int h0 = 2 * (t >> 4), w0 = 2 * (t & 15);   // 2x2 output quad per thread
  float aw[4] = {0, 0, 0, 0}, ab[4] = {0, 0, 0, 0};
  for (int ci = 0; ci < 128; ++ci) {
    __syncthreads();
    sm[t] = smap[((size_t)b * 128 + ci) * 256 + t];
    __syncthreads();
    const float* wwp = cw_w + (co * 128 + ci) * 9;
    const float* wbp = cb_w + (co * 128 + ci) * 9;
    #pragma unroll
    for (int kh = 0; kh < 3; ++kh)
    #pragma unroll
    for (int kw = 0; kw < 3; ++kw) {
      float wwv = wwp[kh * 3 + kw], wbv = wbp[kh * 3 + kw];
      #pragma unroll
      for (int q = 0; q < 4; ++q) {
        int h = h0 + (q >> 1), w = w0 + (q & 1);
        int y = h - 1 + kh, xx = w - 1 + kw;
        float v = (y >= 0 && y < 32 && xx >= 0 && xx < 32) ? sm[(y >> 1) * 16 + (xx >> 1)] : 0.f;
        aw[q] += wwv * v;
        ab[q] += wbv * v;
      }
    }
  }
  float bw = cw_b[co], bb = cb_b[co];
  #pragma unroll
  for (int q = 0; q < 4; ++q) {
    int h = h0 + (q >> 1), w = w0 + (q & 1);
    size_t o = ((size_t)(b * 128 + co) * 32 + h) * 32 + w;
    sw[o] = aw[q] * CSCALE + bw;
    sb[o] = ab[q] * CSCALE + bb;
  }
}

// K3: fused convT+blur. Block = (stripe of 16 rows, co, b). Keff[co] slab in LDS.
// Thread computes a 4x4 output block from a 4x4 x-register patch per ci.
__global__ __launch_bounds__(256) void main_kernel(const float* __restrict__ x,
    const float* __restrict__ keff, float* __restrict__ out,
    float* __restrict__ partial) {
  int stripe = blockIdx.x, co = blockIdx.y, b = blockIdx.z;
  __shared__ float kl[4608];
  __shared__ float rbuf[8];
  for (int i = threadIdx.x; i < 4608; i += 256) kl[i] = keff[(size_t)co * 4608 + i];
  __syncthreads();
  int t = threadIdx.x;
  int r = t >> 6, c = t & 63;
  int h0 = stripe * 16;                // out rows h0+4r .. h0+4r+3, cols 4c..4c+3
  int bi = (h0 >> 1) + 2 * r - 1;      // x row base
  int bj = 2 * c - 1;                  // x col base
  int off[16]; bool ok[16];
  #pragma unroll
  for (int di = 0; di < 4; ++di)
  #pragma unroll
  for (int dj = 0; dj < 4; ++dj) {
    int ri = bi + di, cj = bj + dj;
    bool o = (ri >= 0 && ri < 128 && cj >= 0 && cj < 128);
    ok[di * 4 + dj] = o;
    off[di * 4 + dj] = (o ? ri : 0) * 128 + (o ? cj : 0);
  }
  float acc[16];
  #pragma unroll
  for (int i = 0; i < 16; ++i) acc[i] = 0.f;
  const float* xb = x + (size_t)b * 128 * 16384;
  for (int ci = 0; ci < 128; ++ci) {
    const float* xc = xb + ci * 16384;
    float xv[16];
    #pragma unroll
    for (int i = 0; i < 16; ++i) {
      float v = __ldg(xc + off[i]);
      xv[i] = ok[i] ? v : 0.f;
    }
    const float* kc = kl + ci * 36;
    #pragma unroll
    for (int a = 0; a < 3; ++a)
    #pragma unroll
    for (int b2 = 0; b2 < 3; ++b2) {
      int tap = a * 3 + b2;
      float kee = kc[tap], keo = kc[9 + tap], koe = kc[18 + tap], koo = kc[27 + tap];
      #pragma unroll
      for (int dr = 0; dr < 4; ++dr)
      #pragma unroll
      for (int dc = 0; dc < 4; ++dc) {
        float kk = (dr & 1) ? ((dc & 1) ? koo : koe) : ((dc & 1) ? keo : kee);
        acc[dr * 4 + dc] += kk * xv[((dr >> 1) + a) * 4 + (dc >> 1) + b2];
      }
    }
  }
  float s1 = 0.f, s2 = 0.f;
  size_t obase = (((size_t)(b * 128 + co)) * 256 + h0 + 4 * r) * 256 + 4 * c;
  #pragma unroll
  for (int dr = 0; dr < 4; ++dr) {
    float4 v4 = make_float4(acc[dr * 4 + 0], acc[dr * 4 + 1], acc[dr * 4 + 2], acc[dr * 4 + 3]);
    *(float4*)(out + obase + (size_t)dr * 256) = v4;
    s1 += v4.x + v4.y + v4.z + v4.w;
    s2 += v4.x * v4.x + v4.y * v4.y + v4.z * v4.z + v4.w * v4.w;
  }
  #pragma unroll
  for (int m = 32; m; m >>= 1) { s1 += __shfl_xor(s1, m, 64); s2 += __shfl_xor(s2, m, 64); }
  if (c == 0) { rbuf[r * 2] = s1; rbuf[r * 2 + 1] = s2; }
  __syncthreads();
  if (t == 0) {
    float a1 = rbuf[0] + rbuf[2] + rbuf[4] + rbuf[6];
    float a2 = rbuf[1] + rbuf[3] + rbuf[5] + rbuf[7];
    size_t p = ((size_t)(b * 128 + co) * 16 + stripe) * 2;
    partial[p] = a1; partial[p + 1] = a2;
  }
}

// K4: finalize per-(b,c) mean / rstd from 16 stripe partials (deterministic).
__global__ __launch_bounds__(256) void stats_kernel(const float* __restrict__ partial,
                                                    float* __restrict__ stats) {
  int bc = blockIdx.x * 256 + threadIdx.x;
  if (bc >= 1024) return;
  float s1 = 0.f, s2 = 0.f;
  #pragma unroll
  for (int i = 0; i < 16; ++i) {
    s1 += partial[(bc * 16 + i) * 2];
    s2 += partial[(bc * 16 + i) * 2 + 1];
  }
  float mean = s1 * (1.f / 65536.f);
  float var = s2 * (1.f / 65536.f) - mean * mean;
  stats[bc * 2] = mean;
  stats[bc * 2 + 1] = rsqrtf(var + 1e-5f);
}

// K5: in-place normalize + modulation with nearest-upsampled sw/sb (h/8, w/8).
__global__ __launch_bounds__(256) void final_kernel(float* __restrict__ out,
    const float* __restrict__ sw, const float* __restrict__ sb,
    const float* __restrict__ stats) {
  unsigned int tid = blockIdx.x * 256 + threadIdx.x;
  unsigned int e = tid * 4;             // < 2^26
  unsigned int w = e & 255u;
  unsigned int h = (e >> 8) & 255u;
  unsigned int bc = e >> 16;            // b*128 + c
  float mean = stats[bc * 2], rstd = stats[bc * 2 + 1];
  unsigned int sidx = (bc * 32 + (h >> 3)) * 32 + (w >> 3);
  float m1 = 1.f + 0.3f * sw[sidx];
  float a1 = 0.3f * sb[sidx];
  float4 v = *(float4*)(out + e);
  v.x = (v.x - mean) * rstd * m1 + a1;
  v.y = (v.y - mean) * rstd * m1 + a1;
  v.z = (v.z - mean) * rstd * m1 + a1;
  v.w = (v.w - mean) * rstd * m1 + a1;
  *(float4*)(out + e) = v;
}

extern "C" void kernel_launch(void* const* d_in, const int* in_sizes, int n_in,
                              void* d_out, int out_size, void* d_ws, size_t ws_size,
                              hipStream_t stream) {
  const float* x      = (const float*)d_in[0];
  const float* style  = (const float*)d_in[1];
  const float* weight = (const float*)d_in[2];
  const float* lin_w  = (const float*)d_in[3];
  const float* lin_b  = (const float*)d_in[4];
  const float* cw_w   = (const float*)d_in[5];
  const float* cw_b   = (const float*)d_in[6];
  const float* cb_w   = (const float*)d_in[7];
  const float* cb_b   = (const float*)d_in[8];
  float* out = (float*)d_out;
  float* ws = (float*)d_ws;

  float* keff    = ws;                  // 589824 floats
  float* smap    = keff + 589824;       // 262144
  float* swb     = smap + 262144;       // 1048576
  float* sbb     = swb + 1048576;       // 1048576
  float* partial = sbb + 1048576;       // 32768
  float* stats   = partial + 32768;     // 2048   (total ~11.9 MB)

  keff_kernel<<<dim3(2304), dim3(256), 0, stream>>>(weight, keff);
  style_kernel<<<dim3(512), dim3(256), 0, stream>>>(style, lin_w, lin_b, smap);
  modconv_kernel<<<dim3(128, 8), dim3(256), 0, stream>>>(smap, cw_w, cw_b, cb_w, cb_b, swb, sbb);
  main_kernel<<<dim3(16, 128, 8), dim3(256), 0, stream>>>(x, keff, out, partial);
  stats_kernel<<<dim3(4), dim3(256), 0, stream>>>(partial, stats);
  final_kernel<<<dim3(65536), dim3(256), 0, stream>>>(out, swb, sbb, stats);
}

// Round 2
// 521.125 us; speedup vs baseline: 7.5210x; 7.5210x over previous
//
#include <hip/hip_runtime.h>
#include <cstdint>

// B=8, Cin=Cout=128, x 128x128 -> out 256x256.
#define SCALE_MAIN 0.029462782549439483f   // 1/sqrt(128*9)
#define LSCALE     0.044194173824159223f   // 1/sqrt(512)
#define CSCALE     0.029462782549439483f   // 1/sqrt(128*9)

typedef __attribute__((ext_vector_type(8))) short bf16x8;
typedef __attribute__((ext_vector_type(4))) float f32x4;
typedef __attribute__((ext_vector_type(4))) unsigned int u32x4;

static __device__ __forceinline__ float lrelu_s2(float v) {
  return (v > 0.f ? v : 0.2f * v) * 1.4142135623730951f;
}

static __device__ __forceinline__ unsigned short f2bf(float f) {
  unsigned int u = __builtin_bit_cast(unsigned int, f);
  u += 0x7FFFu + ((u >> 16) & 1u);
  return (unsigned short)(u >> 16);
}

// K0: effective fused convT+blur kernel, written as bf16 in MFMA-B layout:
// kb[par][k/8][co][j], k = tap*128 + ci (tap = a*3+b2), j = k%8 = ci&7.
__global__ __launch_bounds__(256) void keffb_kernel(const float* __restrict__ weight,
                                                    short* __restrict__ kb) {
  int idx = blockIdx.x * 256 + threadIdx.x;
  if (idx >= 128 * 128 * 36) return;
  int tap = idx % 9;
  int tmp = idx / 9;
  int par = tmp & 3;
  int cc  = tmp >> 2;            // co*128 + ci
  int co = cc >> 7, ci = cc & 127;
  int ph = par >> 1, pw = par & 1;
  int a = tap / 3, b = tap % 3;
  int th = ph ? 3 - 2 * a : 2 - 2 * a;
  int tw = pw ? 3 - 2 * b : 2 - 2 * b;
  const float k4[4] = {1.f, 3.f, 3.f, 1.f};
  const float* wp = weight + cc * 9;
  float acc = 0.f;
  #pragma unroll
  for (int u = 0; u < 4; ++u) {
    int m = th - 1 + u;
    if (m < 0 || m > 2) continue;
    #pragma unroll
    for (int v = 0; v < 4; ++v) {
      int n = tw - 1 + v;
      if (n < 0 || n > 2) continue;
      acc += (k4[3 - u] * k4[3 - v] * (1.f / 16.f)) * wp[m * 3 + n];
    }
  }
  kb[(((par * 144) + tap * 16 + (ci >> 3)) * 128 + co) * 8 + (ci & 7)] =
      (short)f2bf(acc * SCALE_MAIN);
}

// K_t: x NCHW fp32 -> NHWC bf16 via LDS-tiled transpose. Block = (y, b).
__global__ __launch_bounds__(256) void xpose_kernel(const float* __restrict__ x,
                                                    unsigned short* __restrict__ xt) {
  int y = blockIdx.x, b = blockIdx.y;
  __shared__ unsigned short tl[128 * 134];
  int t = threadIdx.x;
  #pragma unroll 4
  for (int i = 0; i < 16; ++i) {
    int c = t + i * 256;                  // 4096 float4 chunks
    int ci = c >> 5, x4 = c & 31;
    f32x4 v = *(const f32x4*)(x + (size_t)(b * 128 + ci) * 16384 + y * 128 + x4 * 4);
    unsigned int* dst = (unsigned int*)(tl + ci * 134 + x4 * 4);
    dst[0] = (unsigned int)f2bf(v.x) | ((unsigned int)f2bf(v.y) << 16);
    dst[1] = (unsigned int)f2bf(v.z) | ((unsigned int)f2bf(v.w) << 16);
  }
  __syncthreads();
  #pragma unroll 2
  for (int i = 0; i < 8; ++i) {
    int c = t + i * 256;                  // 2048 16B chunks
    int xcol = c >> 4, sub = c & 15;
    unsigned short u[8];
    #pragma unroll
    for (int j = 0; j < 8; ++j) u[j] = tl[(sub * 8 + j) * 134 + xcol];
    u32x4 o;
    o.x = (unsigned int)u[0] | ((unsigned int)u[1] << 16);
    o.y = (unsigned int)u[2] | ((unsigned int)u[3] << 16);
    o.z = (unsigned int)u[4] | ((unsigned int)u[5] << 16);
    o.w = (unsigned int)u[6] | ((unsigned int)u[7] << 16);
    *(u32x4*)(xt + ((size_t)(b * 128 + y) * 128 + xcol) * 128 + sub * 8) = o;
  }
}

// K1: style GEMV + fused lrelu -> smap[b][32768]
__global__ __launch_bounds__(256) void style_kernel(const float* __restrict__ style,
                                                    const float* __restrict__ lin_w,
                                                    const float* __restrict__ lin_b,
                                                    float* __restrict__ smap) {
  int wid = threadIdx.x >> 6, lane = threadIdx.x & 63;
  int gw = blockIdx.x * 4 + wid;
  const float4* st4 = (const float4*)style;
  float s[8][8];
  #pragma unroll
  for (int b = 0; b < 8; ++b) {
    float4 a0 = st4[b * 128 + lane * 2];
    float4 a1 = st4[b * 128 + lane * 2 + 1];
    s[b][0] = a0.x; s[b][1] = a0.y; s[b][2] = a0.z; s[b][3] = a0.w;
    s[b][4] = a1.x; s[b][5] = a1.y; s[b][6] = a1.z; s[b][7] = a1.w;
  }
  for (int rr = 0; rr < 16; ++rr) {
    int j = gw * 16 + rr;
    const float4* wp = (const float4*)(lin_w + (size_t)j * 512);
    float4 w0 = wp[lane * 2], w1 = wp[lane * 2 + 1];
    float acc[8];
    #pragma unroll
    for (int b = 0; b < 8; ++b) {
      acc[b] = w0.x * s[b][0] + w0.y * s[b][1] + w0.z * s[b][2] + w0.w * s[b][3]
             + w1.x * s[b][4] + w1.y * s[b][5] + w1.z * s[b][6] + w1.w * s[b][7];
    }
    #pragma unroll
    for (int m = 32; m; m >>= 1) {
      #pragma unroll
      for (int b = 0; b < 8; ++b) acc[b] += __shfl_xor(acc[b], m, 64);
    }
    if (lane == 0) {
      float bias = lin_b[j];
      #pragma unroll
      for (int b = 0; b < 8; ++b)
        smap[(size_t)b * 32768 + j] = lrelu_s2(acc[b] * LSCALE + bias);
    }
  }
}

// K2: the two 3x3 modulation convs on the 32x32 upsampled style map.
__global__ __launch_bounds__(256) void modconv_kernel(const float* __restrict__ smap,
    const float* __restrict__ cw_w, const float* __restrict__ cw_b,
    const float* __restrict__ cb_w, const float* __restrict__ cb_b,
    float* __restrict__ sw, float* __restrict__ sb) {
  int co = blockIdx.x, b = blockIdx.y;
  int t = threadIdx.x;
  __shared__ float sm[256];
  int h0 = 2 * (t >> 4), w0 = 2 * (t & 15);
  float aw[4] = {0, 0, 0, 0}, ab[4] = {0, 0, 0, 0};
  for (int ci = 0; ci < 128; ++ci) {
    __syncthreads();
    sm[t] = smap[((size_t)b * 128 + ci) * 256 + t];
    __syncthreads();
    const float* wwp = cw_w + (co * 128 + ci) * 9;
    const float* wbp = cb_w + (co * 128 + ci) * 9;
    #pragma unroll
    for (int kh = 0; kh < 3; ++kh)
    #pragma unroll
    for (int kw = 0; kw < 3; ++kw) {
      float wwv = wwp[kh * 3 + kw], wbv = wbp[kh * 3 + kw];
      #pragma unroll
      for (int q = 0; q < 4; ++q) {
        int h = h0 + (q >> 1), w = w0 + (q & 1);
        int y = h - 1 + kh, xx = w - 1 + kw;
        float v = (y >= 0 && y < 32 && xx >= 0 && xx < 32) ? sm[(y >> 1) * 16 + (xx >> 1)] : 0.f;
        aw[q] += wwv * v;
        ab[q] += wbv * v;
      }
    }
  }
  float bw = cw_b[co], bb = cb_b[co];
  #pragma unroll
  for (int q = 0; q < 4; ++q) {
    int h = h0 + (q >> 1), w = w0 + (q & 1);
    size_t o = ((size_t)(b * 128 + co) * 32 + h) * 32 + w;
    sw[o] = aw[q] * CSCALE + bw;
    sb[o] = ab[q] * CSCALE + bb;
  }
}

// K3: MFMA implicit-GEMM fused convT+blur.
// Block: 64-pixel row strip (b, y0, xh) x 512 outputs (4 par x 128 co).
// 8 waves: wave w -> parity p=w>>1, co-half ch=w&1. 16x16x32 bf16 MFMA.
// A-tile (3 x 66 x 128ci bf16, row stride 272B) staged once in LDS; K-loop
// (36 steps of K=32, k=tap*128+ci) is barrier-free; B frags are L2-resident
// 16B global loads. Epilogue: LDS transpose -> 512B-coalesced C rows +
// per-co stats partials via shfl (deterministic).
__global__ __launch_bounds__(512) void main_kernel(const unsigned short* __restrict__ xt,
    const short* __restrict__ kb, float* __restrict__ out,
    float* __restrict__ partial) {
  __shared__ char smem[53856];           // max(198*272, 4*64*34*4)
  int xh = blockIdx.x, y0 = blockIdx.y, b = blockIdx.z;
  int x0 = xh * 64;
  int t = threadIdx.x;
  int lane = t & 63, w = t >> 6;
  int p = w >> 1, ch = w & 1;

  // ---- stage A tile: 198 spatial x 128 ci bf16, zero-padded at edges ----
  const char* xtc = (const char*)xt;
  for (int c = t; c < 3168; c += 512) {
    int spos = c >> 4, sub = c & 15;
    int aa = spos / 66, cc2 = spos - aa * 66;
    int y = y0 - 1 + aa, xg = x0 - 1 + cc2;
    f32x4 v = {0.f, 0.f, 0.f, 0.f};
    if ((unsigned)y < 128u && (unsigned)xg < 128u)
      v = *(const f32x4*)(xtc + ((size_t)((b * 128 + y) * 128 + xg)) * 256 + sub * 16);
    *(f32x4*)(smem + spos * 272 + sub * 16) = v;
  }
  __syncthreads();

  // ---- K loop ----
  const char* abase = smem + (lane & 15) * 272 + (lane >> 4) * 16;
  const bf16x8* kbv = (const bf16x8*)kb;
  int bbase = (p * 144) * 128 + ch * 64 + (lane >> 4) * 128 + (lane & 15);

  f32x4 acc[4][4];
  #pragma unroll
  for (int i = 0; i < 4; ++i)
  #pragma unroll
  for (int j = 0; j < 4; ++j) acc[i][j] = (f32x4){0.f, 0.f, 0.f, 0.f};

  for (int s = 0; s < 36; ++s) {
    int tap = s >> 2, ci0 = (s & 3) * 32;
    int ta = tap / 3, tb = tap - ta * 3;
    const char* ab = abase + (ta * 66 + tb) * 272 + ci0 * 2;
    bf16x8 av[4];
    #pragma unroll
    for (int mf = 0; mf < 4; ++mf) av[mf] = *(const bf16x8*)(ab + mf * 4352);
    #pragma unroll
    for (int nf = 0; nf < 4; ++nf) {
      bf16x8 bv = kbv[bbase + s * 512 + nf * 16];
      #pragma unroll
      for (int mf = 0; mf < 4; ++mf)
        acc[mf][nf] = __builtin_amdgcn_mfma_f32_16x16x32_bf16(av[mf], bv, acc[mf][nf], 0, 0, 0);
    }
  }

  // ---- epilogue: per n-frag: dump to LDS, stats from regs, coalesced write ----
  float* eps = (float*)smem;             // [par 4][xx 64][slot 34 (32 used)]
  for (int nf = 0; nf < 4; ++nf) {
    __syncthreads();                     // protects A-tile/eps reuse + prev round reads
    float s1 = 0.f, s2 = 0.f;
    #pragma unroll
    for (int mf = 0; mf < 4; ++mf) {
      #pragma unroll
      for (int r = 0; r < 4; ++r) {
        int xx = mf * 16 + (lane >> 4) * 4 + r;
        float v = acc[mf][nf][r];
        eps[(p * 64 + xx) * 34 + ch * 16 + (lane & 15)] = v;
        s1 += v; s2 += v * v;
      }
    }
    s1 += __shfl_xor(s1, 16, 64); s1 += __shfl_xor(s1, 32, 64);
    s2 += __shfl_xor(s2, 16, 64); s2 += __shfl_xor(s2, 32, 64);
    if (lane < 16) {
      int co = ch * 64 + nf * 16 + lane;
      size_t pidx = (((((size_t)b * 128 + co) * 128 + y0) * 2 + xh) * 4 + p) * 2;
      partial[pidx] = s1; partial[pidx + 1] = s2;
    }
    __syncthreads();
    int rrow = t >> 3, cs = rrow & 31, ph2 = rrow >> 5, w0 = (t & 7) * 16;
    int co = (cs >> 4) * 64 + nf * 16 + (cs & 15);
    int h = 2 * y0 + ph2;
    float vv[16];
    #pragma unroll
    for (int i = 0; i < 16; ++i) {
      int wl = w0 + i;
      vv[i] = eps[(((ph2 * 2 + (wl & 1)) * 64) + (wl >> 1)) * 34 + cs];
    }
    float* op = out + ((size_t)(b * 128 + co) * 256 + h) * 256 + xh * 128 + w0;
    #pragma unroll
    for (int i = 0; i < 4; ++i) {
      f32x4 o4 = {vv[i * 4], vv[i * 4 + 1], vv[i * 4 + 2], vv[i * 4 + 3]};
      *(f32x4*)(op + i * 4) = o4;
    }
  }
}

// K4: reduce 1024 partials per (b,c) -> mean, rstd.
__global__ __launch_bounds__(256) void stats_kernel(const float* __restrict__ partial,
                                                    float* __restrict__ stats) {
  int bc = blockIdx.x;
  int t = threadIdx.x;
  float s1 = 0.f, s2 = 0.f;
  for (int j = t; j < 1024; j += 256) {
    s1 += partial[(size_t)bc * 2048 + 2 * j];
    s2 += partial[(size_t)bc * 2048 + 2 * j + 1];
  }
  #pragma unroll
  for (int m = 32; m; m >>= 1) { s1 += __shfl_xor(s1, m, 64); s2 += __shfl_xor(s2, m, 64); }
  __shared__ float rb[8];
  if ((t & 63) == 0) { rb[(t >> 6) * 2] = s1; rb[(t >> 6) * 2 + 1] = s2; }
  __syncthreads();
  if (t == 0) {
    float a1 = rb[0] + rb[2] + rb[4] + rb[6];
    float a2 = rb[1] + rb[3] + rb[5] + rb[7];
    float mean = a1 * (1.f / 65536.f);
    float var = a2 * (1.f / 65536.f) - mean * mean;
    stats[bc * 2] = mean;
    stats[bc * 2 + 1] = rsqrtf(var + 1e-5f);
  }
}

// K5: in-place normalize + modulation (nearest-upsampled sw/sb).
__global__ __launch_bounds__(256) void final_kernel(float* __restrict__ out,
    const float* __restrict__ sw, const float* __restrict__ sb,
    const float* __restrict__ stats) {
  unsigned int tid = blockIdx.x * 256 + threadIdx.x;
  unsigned int e = tid * 4;
  unsigned int w = e & 255u;
  unsigned int h = (e >> 8) & 255u;
  unsigned int bc = e >> 16;
  float mean = stats[bc * 2], rstd = stats[bc * 2 + 1];
  unsigned int sidx = (bc * 32 + (h >> 3)) * 32 + (w >> 3);
  float m1 = 1.f + 0.3f * sw[sidx];
  float a1 = 0.3f * sb[sidx];
  float4 v = *(float4*)(out + e);
  v.x = (v.x - mean) * rstd * m1 + a1;
  v.y = (v.y - mean) * rstd * m1 + a1;
  v.z = (v.z - mean) * rstd * m1 + a1;
  v.w = (v.w - mean) * rstd * m1 + a1;
  *(float4*)(out + e) = v;
}

extern "C" void kernel_launch(void* const* d_in, const int* in_sizes, int n_in,
                              void* d_out, int out_size, void* d_ws, size_t ws_size,
                              hipStream_t stream) {
  const float* x      = (const float*)d_in[0];
  const float* style  = (const float*)d_in[1];
  const float* weight = (const float*)d_in[2];
  const float* lin_w  = (const float*)d_in[3];
  const float* lin_b  = (const float*)d_in[4];
  const float* cw_w   = (const float*)d_in[5];
  const float* cw_b   = (const float*)d_in[6];
  const float* cb_w   = (const float*)d_in[7];
  const float* cb_b   = (const float*)d_in[8];
  float* out = (float*)d_out;
  char* ws = (char*)d_ws;

  short*          kbb   = (short*)(ws);                       // 1,179,648 B
  unsigned short* xt    = (unsigned short*)(ws + 1179648);    // 33,554,432 B
  float*          smap  = (float*)(ws + 34734080);            // 1 MB
  float*          swb   = (float*)(ws + 35782656);            // 4 MB
  float*          sbb   = (float*)(ws + 39976960);            // 4 MB
  float*          part  = (float*)(ws + 44171264);            // 8 MB
  float*          stats = (float*)(ws + 52559872);            // 8 KB

  keffb_kernel<<<dim3(2304), dim3(256), 0, stream>>>(weight, kbb);
  xpose_kernel<<<dim3(128, 8), dim3(256), 0, stream>>>(x, xt);
  style_kernel<<<dim3(512), dim3(256), 0, stream>>>(style, lin_w, lin_b, smap);
  modconv_kernel<<<dim3(128, 8), dim3(256), 0, stream>>>(smap, cw_w, cw_b, cb_w, cb_b, swb, sbb);
  main_kernel<<<dim3(2, 128, 8), dim3(512), 0, stream>>>(xt, kbb, out, part);
  stats_kernel<<<dim3(1024), dim3(256), 0, stream>>>(part, stats);
  final_kernel<<<dim3(65536), dim3(256), 0, stream>>>(out, swb, sbb, stats);
}